// Round 2
// baseline (696.641 us; speedup 1.0000x reference)
//
#include <hip/hip_runtime.h>
#include <cstdint>

// GAT fused kernel. Shapes: B=16384, N=64, F_IN=128, H=4, D=32 (H*D=128).
// Inputs: node_features f32 (B,128), neighbor_features f32 (B,64,128),
//         neighbor_mask bool (B,64) [byte- or int32-stored: auto-detected],
//         W f32 (128,128), a f32 (4,64,1).
// Output: f32 (B,128).

typedef __attribute__((ext_vector_type(8))) short bf16x8;
typedef __attribute__((ext_vector_type(4))) float f32x4;

union U16B { uint4 u; bf16x8 f; };

__device__ inline unsigned short f2bf(float x) {
  unsigned int u = __float_as_uint(x);
  unsigned int r = u + 0x7FFFu + ((u >> 16) & 1u);   // round-to-nearest-even
  return (unsigned short)(r >> 16);
}

// prep: blocks 0..63 -> Wt[c][k] = bf16(W[k][c]) (transposed, K-contiguous);
//       block 64     -> wa1[k][h] = sum_d W[k][h*32+d] * a[h*64+d]
__global__ void gat_prep(const float* __restrict__ W, const float* __restrict__ a,
                         unsigned short* __restrict__ Wt, float* __restrict__ wa1) {
  int t = threadIdx.x;
  int blk = blockIdx.x;
  if (blk < 64) {
    int g = blk * 256 + t;          // 0..16383
    int c = g >> 7, k = g & 127;
    Wt[c * 128 + k] = f2bf(W[k * 128 + c]);
  } else {
    // 512 (k,h) pairs, 256 threads, 2 each
    for (int i = t; i < 512; i += 256) {
      int k = i >> 2, h = i & 3;
      float s = 0.f;
      #pragma unroll
      for (int d = 0; d < 32; ++d) s += W[k * 128 + h * 32 + d] * a[h * 64 + d];
      wa1[i] = s;  // wa1[k*4+h]
    }
  }
}

__global__ __launch_bounds__(256, 4) void gat_main(
    const float* __restrict__ node, const float* __restrict__ nbr,
    const unsigned char* __restrict__ mask, const unsigned short* __restrict__ Wt,
    const float* __restrict__ wa1, const float* __restrict__ a,
    float* __restrict__ out) {
  const int b    = blockIdx.x;
  const int tid  = threadIdx.x;
  const int w    = tid >> 6;     // wave id == head id
  const int lane = tid & 63;
  const int grp  = lane >> 4;    // 0..3
  const int l15  = lane & 15;

  __shared__ unsigned short Albs[64 * 128];  // swizzled bf16 A-tile, 16 KB

  // ---- mask storage auto-detect: byte-bool vs int32 ----
  // If byte-packed, the first 64 words (256 random 0/1 bytes) almost surely
  // contain a value > 1; if int32-stored every word is exactly 0 or 1.
  unsigned int probe = ((const unsigned int*)mask)[lane];
  bool isByte = (__ballot(probe > 1u) != 0ull);

  // ---- B fragments straight from global (Wt is 32 KB, L2-hot) ----
  // B[k][c]: lane holds c = l15 (+ntile*16), k = grp*8 + i, i=0..7 (K-contiguous in Wt)
  bf16x8 bfr[2][4];
  #pragma unroll
  for (int j = 0; j < 2; ++j) {
    #pragma unroll
    for (int ks = 0; ks < 4; ++ks) {
      int c  = (2 * w + j) * 16 + l15;
      int k0 = grp * 8 + ks * 32;
      U16B u; u.u = *(const uint4*)(Wt + c * 128 + k0);
      bfr[j][ks] = u.f;
    }
  }

  // ---- a2 scalars for this head/lane's two columns ----
  float a2lo = a[w * 64 + 32 + l15];   // d = l15
  float a2hi = a[w * 64 + 48 + l15];   // d = 16 + l15

  // ---- e_src[b][w] = node[b] . wa1[:, w]  (full-wave butterfly) ----
  float es = node[b * 128 + lane]      * wa1[lane * 4 + w]
           + node[b * 128 + 64 + lane] * wa1[(64 + lane) * 4 + w];
  #pragma unroll
  for (int m = 32; m >= 1; m >>= 1) es += __shfl_xor(es, m);

  // ---- neighbor-present bits (bit rg of okm[mt]) for n = mt*16+grp*4+rg ----
  unsigned int okm[4];
  if (isByte) {
    #pragma unroll
    for (int mt = 0; mt < 4; ++mt) {
      unsigned int mb = *(const unsigned int*)(mask + b * 64 + mt * 16 + grp * 4);
      okm[mt] = ((mb & 0xffu)       ? 1u : 0u) |
                ((mb & 0xff00u)     ? 2u : 0u) |
                ((mb & 0xff0000u)   ? 4u : 0u) |
                ((mb & 0xff000000u) ? 8u : 0u);
    }
  } else {
    const uint4* mi = (const uint4*)((const unsigned int*)mask + b * 64);
    #pragma unroll
    for (int mt = 0; mt < 4; ++mt) {
      uint4 mm = mi[mt * 4 + grp];
      okm[mt] = (mm.x ? 1u : 0u) | (mm.y ? 2u : 0u) | (mm.z ? 4u : 0u) | (mm.w ? 8u : 0u);
    }
  }

  // ---- stage A: f32 -> bf16, XOR-swizzled LDS ----
  {
    const float4* src = (const float4*)(nbr + (size_t)b * 8192);
    #pragma unroll
    for (int rep = 0; rep < 8; ++rep) {
      int v = rep * 256 + tid;          // vec4 index; fully coalesced
      float4 f = src[v];
      int r  = v >> 5;                  // row 0..63
      int kb = (v & 31) * 8;            // byte offset of k within row (k*2)
      uint2 p;
      p.x = (unsigned int)f2bf(f.x) | ((unsigned int)f2bf(f.y) << 16);
      p.y = (unsigned int)f2bf(f.z) | ((unsigned int)f2bf(f.w) << 16);
      int byteaddr = (r * 256 + kb) ^ ((r & 7) << 4);
      *(uint2*)((char*)Albs + byteaddr) = p;
    }
  }
  __syncthreads();

  // ---- GEMM: h_nb[n][c] for n in 4 M-tiles, c in this wave's 2 N-tiles ----
  f32x4 acc[4][2];
  #pragma unroll
  for (int mt = 0; mt < 4; ++mt) { acc[mt][0] = f32x4{0,0,0,0}; acc[mt][1] = f32x4{0,0,0,0}; }
  #pragma unroll
  for (int mt = 0; mt < 4; ++mt) {
    #pragma unroll
    for (int ks = 0; ks < 4; ++ks) {
      int r     = mt * 16 + l15;
      int kbyte = (grp * 8 + ks * 32) * 2;
      int addr  = (r * 256 + kbyte) ^ ((r & 7) << 4);
      U16B u; u.u = *(const uint4*)((const char*)Albs + addr);
      acc[mt][0] = __builtin_amdgcn_mfma_f32_16x16x32_bf16(u.f, bfr[0][ks], acc[mt][0], 0, 0, 0);
      acc[mt][1] = __builtin_amdgcn_mfma_f32_16x16x32_bf16(u.f, bfr[1][ks], acc[mt][1], 0, 0, 0);
    }
  }

  // ---- e_nb + leaky_relu + mask; n = mt*16 + grp*4 + rg; head = w ----
  float e[4][4];
  #pragma unroll
  for (int mt = 0; mt < 4; ++mt) {
    #pragma unroll
    for (int rg = 0; rg < 4; ++rg) {
      float v = acc[mt][0][rg] * a2lo + acc[mt][1][rg] * a2hi;
      v += __shfl_xor(v, 1); v += __shfl_xor(v, 2);
      v += __shfl_xor(v, 4); v += __shfl_xor(v, 8);
      float s = es + v;
      s = s > 0.f ? s : 0.2f * s;
      bool ok = (okm[mt] >> rg) & 1u;
      e[mt][rg] = ok ? s : -__builtin_inff();
    }
  }

  // ---- softmax over n=64 (16 lane-local n + 2 cross-group steps) ----
  float M = -__builtin_inff();
  #pragma unroll
  for (int mt = 0; mt < 4; ++mt)
    #pragma unroll
    for (int rg = 0; rg < 4; ++rg) M = fmaxf(M, e[mt][rg]);
  M = fmaxf(M, __shfl_xor(M, 16));
  M = fmaxf(M, __shfl_xor(M, 32));

  float S = 0.f;
  float al[4][4];
  #pragma unroll
  for (int mt = 0; mt < 4; ++mt) {
    #pragma unroll
    for (int rg = 0; rg < 4; ++rg) {
      float p = __expf(e[mt][rg] - M);   // exp(-inf)=0 for masked
      al[mt][rg] = p;
      S += p;
    }
  }
  S += __shfl_xor(S, 16);
  S += __shfl_xor(S, 32);
  float inv = 1.f / S;

  // ---- out[c] = sum_n alpha[n] * h_nb[n][c] ----
  float po0 = 0.f, po1 = 0.f;
  #pragma unroll
  for (int mt = 0; mt < 4; ++mt) {
    #pragma unroll
    for (int rg = 0; rg < 4; ++rg) {
      po0 += al[mt][rg] * acc[mt][0][rg];
      po1 += al[mt][rg] * acc[mt][1][rg];
    }
  }
  po0 += __shfl_xor(po0, 16); po0 += __shfl_xor(po0, 32);
  po1 += __shfl_xor(po1, 16); po1 += __shfl_xor(po1, 32);
  po0 *= inv; po1 *= inv;

  if (lane < 32) {
    float vOut = (lane & 16) ? po1 : po0;
    out[b * 128 + w * 32 + lane] = vOut;
  }
}

extern "C" void kernel_launch(void* const* d_in, const int* in_sizes, int n_in,
                              void* d_out, int out_size, void* d_ws, size_t ws_size,
                              hipStream_t stream) {
  (void)in_sizes; (void)n_in; (void)out_size; (void)ws_size;
  const float* node = (const float*)d_in[0];
  const float* nbr  = (const float*)d_in[1];
  const unsigned char* mask = (const unsigned char*)d_in[2];
  const float* W    = (const float*)d_in[3];
  const float* a    = (const float*)d_in[4];
  float* out = (float*)d_out;

  unsigned short* Wt = (unsigned short*)d_ws;                    // 32 KB
  float* wa1 = (float*)((char*)d_ws + 32768);                    // 2 KB

  gat_prep<<<65, 256, 0, stream>>>(W, a, Wt, wa1);
  gat_main<<<16384, 256, 0, stream>>>(node, nbr, mask, Wt, wa1, a, out);
}